// Round 4
// baseline (209.946 us; speedup 1.0000x reference)
//
#include <hip/hip_runtime.h>

#define DF 128
#define NBKT_MAX 256   // coarse buckets = ceil(N/256); N=50000 -> 196
#define CAP 8192       // per-bucket edge capacity incl. 8-align padding (avg 4082+<=1792 pad)
#define SCHUNK 2048    // edges per scatter block (R2: 8192 -> 3.6% occupancy, latency-bound)
// packing assumes src < 2^24 and N <= 65536 (srcs stored as ushort). N=50000 here.

typedef unsigned int uint;
typedef unsigned short ushort;
typedef __attribute__((ext_vector_type(8))) short short8;   // 8 bf16 (4 VGPR) MFMA A/B frag
typedef __attribute__((ext_vector_type(4))) float f32x4;    // MFMA C/D frag

union frag_u { uint4 u4; short8 s8; };

__device__ __forceinline__ uint f2u(float f) { return __float_as_uint(f); }
__device__ __forceinline__ ushort rne_bf16(float v) {
    uint u = __float_as_uint(v);
    u = u + 0x7FFFu + ((u >> 16) & 1u);
    return (ushort)(u >> 16);
}
__device__ __forceinline__ float bflo(uint u) { return __uint_as_float(u << 16); }
__device__ __forceinline__ float bfhi(uint u) { return __uint_as_float(u & 0xFFFF0000u); }

// ============ scatter + wprep fused (unchanged from R3: 201us best) ============
__global__ __launch_bounds__(256) void scatter_wprep(const int* __restrict__ src,
                                                     const int* __restrict__ dst,
                                                     int* __restrict__ ccur,
                                                     uint* __restrict__ ebuf,
                                                     int E, int NB, int SB,
                                                     const float* __restrict__ W1,
                                                     const float* __restrict__ W2,
                                                     uint4* __restrict__ Whi,
                                                     uint4* __restrict__ Wlo) {
    __shared__ int cnt[NBKT_MAX];
    __shared__ int base[NBKT_MAX];
    int t = threadIdx.x;
    if ((int)blockIdx.x < SB) {
        int e0 = blockIdx.x * SCHUNK;
        int eb0 = e0 + t * 8;                       // this thread's 8 contiguous edges
        int lim = min(E - eb0, 8);                  // <8 only in last block
        int d[8], s[8];
        if (lim == 8) {
            int4 d0 = *(const int4*)(dst + eb0), d1 = *(const int4*)(dst + eb0 + 4);
            int4 s0 = *(const int4*)(src + eb0), s1 = *(const int4*)(src + eb0 + 4);
            d[0] = d0.x; d[1] = d0.y; d[2] = d0.z; d[3] = d0.w;
            d[4] = d1.x; d[5] = d1.y; d[6] = d1.z; d[7] = d1.w;
            s[0] = s0.x; s[1] = s0.y; s[2] = s0.z; s[3] = s0.w;
            s[4] = s1.x; s[5] = s1.y; s[6] = s1.z; s[7] = s1.w;
        } else {
            for (int i = 0; i < 8; ++i) { d[i] = 0; s[i] = 0; }
            for (int i = 0; i < lim; ++i) { d[i] = dst[eb0 + i]; s[i] = src[eb0 + i]; }
        }
        for (int i = t; i < NB; i += 256) cnt[i] = 0;
        __syncthreads();
        for (int i = 0; i < 8; ++i)
            if (i < lim) atomicAdd(&cnt[d[i] >> 8], 1);
        __syncthreads();
        for (int i = t; i < NB; i += 256) base[i] = cnt[i] ? atomicAdd(&ccur[i], cnt[i]) : 0;
        __syncthreads();
        for (int i = 0; i < 8; ++i)
            if (i < lim) {
                int b = d[i] >> 8;
                int pos = atomicAdd(&base[b], 1);
                if (pos < CAP) ebuf[(size_t)b * CAP + pos] = ((uint)(d[i] & 255) << 24) | (uint)s[i];
            }
    } else {
        int tt4 = ((int)blockIdx.x - SB) * 256 + t;   // 0..4095
        int wsel = tt4 >> 11;
        int tt = tt4 & 2047;
        const float* W = wsel ? W2 : W1;
        int lane = tt & 63;
        int n  = ((tt >> 6) & 7) * 16 + (lane & 15);
        int k0 = (tt >> 9) * 32 + (lane >> 4) * 8;
        uint hi[4], lo[4];
#pragma unroll
        for (int p = 0; p < 4; ++p) {
            float f0 = W[(size_t)(k0 + 2 * p) * DF + n];
            float f1 = W[(size_t)(k0 + 2 * p + 1) * DF + n];
            uint u0 = f2u(f0), u1 = f2u(f1);
            hi[p] = (u1 & 0xFFFF0000u) | (u0 >> 16);                 // truncation split
            float l0 = f0 - __uint_as_float(u0 & 0xFFFF0000u);       // exact residual
            float l1 = f1 - __uint_as_float(u1 & 0xFFFF0000u);
            lo[p] = (f2u(l1) & 0xFFFF0000u) | (f2u(l0) >> 16);
        }
        Whi[wsel * 2048 + tt] = make_uint4(hi[0], hi[1], hi[2], hi[3]);
        Wlo[wsel * 2048 + tt] = make_uint4(lo[0], lo[1], lo[2], lo[3]);
    }
}

// ---------- layer-1 GEMM block body (fp32 A, 3-product split, UNSCALED output) ----------
// shared by sortA_gemm1 / sortB_gemm1 (gemm1 blocks split across the two sort phases)
__device__ __forceinline__ void gemm1_body(int gb, int t,
                                           const float* __restrict__ A,
                                           const uint4* __restrict__ Bhi,
                                           const uint4* __restrict__ Blo,
                                           ushort* __restrict__ Hq, int M) {
    const int lane = t & 63;
    const int w = t >> 6;
    const int l15 = lane & 15, quad = lane >> 4;
    const int rowbase = gb * 128 + w * 32;

    f32x4 acc[2][8];
#pragma unroll
    for (int rt = 0; rt < 2; ++rt)
#pragma unroll
        for (int ct = 0; ct < 8; ++ct) acc[rt][ct] = (f32x4){0.f, 0.f, 0.f, 0.f};

    for (int q = 0; q < 4; ++q) {
        frag_u ah[2], al[2];
#pragma unroll
        for (int rt = 0; rt < 2; ++rt) {
            int m = rowbase + rt * 16 + l15;
            if (m >= M) m = M - 1;                  // clamp; stores guarded below
            const float* ap = A + (size_t)m * DF + q * 32 + quad * 8;
            float4 v0 = *(const float4*)ap;
            float4 v1 = *(const float4*)(ap + 4);
            float f[8] = {v0.x, v0.y, v0.z, v0.w, v1.x, v1.y, v1.z, v1.w};
            uint hi[4], lo[4];
#pragma unroll
            for (int p = 0; p < 4; ++p) {
                uint u0 = f2u(f[2 * p]), u1 = f2u(f[2 * p + 1]);
                hi[p] = (u1 & 0xFFFF0000u) | (u0 >> 16);
                float l0 = f[2 * p]     - __uint_as_float(u0 & 0xFFFF0000u);
                float l1 = f[2 * p + 1] - __uint_as_float(u1 & 0xFFFF0000u);
                lo[p] = (f2u(l1) & 0xFFFF0000u) | (f2u(l0) >> 16);
            }
            ah[rt].u4 = make_uint4(hi[0], hi[1], hi[2], hi[3]);
            al[rt].u4 = make_uint4(lo[0], lo[1], lo[2], lo[3]);
        }
#pragma unroll
        for (int ct = 0; ct < 8; ++ct) {
            frag_u bh, bl;
            bh.u4 = Bhi[(q * 8 + ct) * 64 + lane];
            bl.u4 = Blo[(q * 8 + ct) * 64 + lane];
#pragma unroll
            for (int rt = 0; rt < 2; ++rt) {
                acc[rt][ct] = __builtin_amdgcn_mfma_f32_16x16x32_bf16(al[rt].s8, bh.s8, acc[rt][ct], 0, 0, 0);
                acc[rt][ct] = __builtin_amdgcn_mfma_f32_16x16x32_bf16(ah[rt].s8, bl.s8, acc[rt][ct], 0, 0, 0);
                acc[rt][ct] = __builtin_amdgcn_mfma_f32_16x16x32_bf16(ah[rt].s8, bh.s8, acc[rt][ct], 0, 0, 0);
            }
        }
    }
    // epilogue: col = ct*16+l15 -> q = ct>>1, d = (ct&1)*16+l15; row = rt*16+quad*4+reg
#pragma unroll
    for (int rt = 0; rt < 2; ++rt)
#pragma unroll
        for (int reg = 0; reg < 4; ++reg) {
            int row = rowbase + rt * 16 + quad * 4 + reg;
            if (row < M) {
#pragma unroll
                for (int ct = 0; ct < 8; ++ct)
                    Hq[((size_t)(ct >> 1) * M + row) * 32 + (ct & 1) * 16 + l15] =
                        rne_bf16(acc[rt][ct][reg]);
            }
        }
}

// ============ phase A: count + scan -> rstart/rend/dinv  || gemm1 blocks [0,G1A) ============
// Sort pass-2 moved to sortB (next dispatch) so pass-2 can ALSO emit srcd[pos]=dinv[src]
// (fp32 sidecar) — dinv of every node is complete once this dispatch retires. That kills
// gather1's 8 per-lane dependent dinv loads per iteration (17 -> 11 VMEM wave-insts/iter).
__global__ __launch_bounds__(256) void sortA_gemm1(const uint* __restrict__ ebuf,
                                                   const int* __restrict__ ccur,
                                                   int* __restrict__ rstart,
                                                   int* __restrict__ rend,
                                                   float* __restrict__ dinv,
                                                   const float* __restrict__ A,
                                                   const uint4* __restrict__ Bhi,
                                                   const uint4* __restrict__ Blo,
                                                   ushort* __restrict__ Hq,
                                                   int NB, int N) {
    __shared__ int cnt[256];
    __shared__ int sp[256];
    int t = threadIdx.x;
    if ((int)blockIdx.x < NB) {
        int b = blockIdx.x;
        int count = min(ccur[b], CAP);
        const uint* eb = ebuf + (size_t)b * CAP;
        cnt[t] = 0;
        __syncthreads();
        for (int j = t; j < count; j += 256) atomicAdd(&cnt[eb[j] >> 24], 1);
        __syncthreads();
        int v = cnt[t];
        int pv = (v + 7) & ~7;              // padded to multiple of 8
        sp[t] = pv;
        __syncthreads();
        for (int off = 1; off < 256; off <<= 1) {
            int x = (t >= off) ? sp[t - off] : 0;
            __syncthreads();
            sp[t] += x;
            __syncthreads();
        }
        int ex = sp[t] - pv;                // exclusive padded offset (multiple of 8)
        int node = b * 256 + t;
        if (node < N) {
            rstart[node] = b * CAP + ex;
            rend[node]   = b * CAP + ex + v;
            dinv[node] = rsqrtf((float)v + 1.0f);   // +1 = self-loop
        }
    } else {
        gemm1_body((int)blockIdx.x - NB, t, A, Bhi, Blo, Hq, N);
    }
}

// ============ phase B: scatter srcs + srcd(=dinv[src], fp32) || gemm1 blocks [G1A,...) ======
__global__ __launch_bounds__(256) void sortB_gemm1(const uint* __restrict__ ebuf,
                                                   const int* __restrict__ ccur,
                                                   const int* __restrict__ rstart,
                                                   const float* __restrict__ dinv,
                                                   ushort* __restrict__ srcs,
                                                   float* __restrict__ srcd,
                                                   const float* __restrict__ A,
                                                   const uint4* __restrict__ Bhi,
                                                   const uint4* __restrict__ Blo,
                                                   ushort* __restrict__ Hq,
                                                   int NB, int N, int G1A) {
    __shared__ int sp[256];
    int t = threadIdx.x;
    if ((int)blockIdx.x < NB) {
        int b = blockIdx.x;
        int count = min(ccur[b], CAP);
        const uint* eb = ebuf + (size_t)b * CAP;
        int node = b * 256 + t;
        sp[t] = (node < N) ? (rstart[node] - b * CAP) : CAP;   // local cursor (8-aligned ex)
        __syncthreads();
        for (int j = t; j < count; j += 256) {
            uint e = eb[j];
            int s = (int)(e & 0xFFFFFFu);
            int pos = atomicAdd(&sp[e >> 24], 1);
            if (pos < CAP) {
                srcs[(size_t)b * CAP + pos] = (ushort)s;
                srcd[(size_t)b * CAP + pos] = dinv[s];
            }
        }
    } else {
        gemm1_body((int)blockIdx.x - NB + G1A, t, A, Bhi, Blo, Hq, N);
    }
}

// ============ MFMA GEMM (bf16 A quarter-major): Hq = bf16((A@W)*dinv) ============
__global__ __launch_bounds__(256) void gemm_bf16A(const ushort* __restrict__ A,
                                                  const uint4* __restrict__ Bhi,
                                                  const uint4* __restrict__ Blo,
                                                  const float* __restrict__ dinv,
                                                  ushort* __restrict__ Hq, int M) {
    const int lane = threadIdx.x & 63;
    const int w = threadIdx.x >> 6;
    const int l15 = lane & 15, quad = lane >> 4;
    const int rowbase = blockIdx.x * 128 + w * 32;

    f32x4 acc[2][8];
#pragma unroll
    for (int rt = 0; rt < 2; ++rt)
#pragma unroll
        for (int ct = 0; ct < 8; ++ct) acc[rt][ct] = (f32x4){0.f, 0.f, 0.f, 0.f};

    for (int q = 0; q < 4; ++q) {
        frag_u a[2];
#pragma unroll
        for (int rt = 0; rt < 2; ++rt) {
            int m = rowbase + rt * 16 + l15;
            if (m >= M) m = M - 1;
            const ushort* ap = A + ((size_t)q * M + m) * 32 + quad * 8;
            a[rt].u4 = *(const uint4*)ap;
        }
#pragma unroll
        for (int ct = 0; ct < 8; ++ct) {
            frag_u bh, bl;
            bh.u4 = Bhi[(q * 8 + ct) * 64 + lane];
            bl.u4 = Blo[(q * 8 + ct) * 64 + lane];
#pragma unroll
            for (int rt = 0; rt < 2; ++rt) {
                acc[rt][ct] = __builtin_amdgcn_mfma_f32_16x16x32_bf16(a[rt].s8, bl.s8, acc[rt][ct], 0, 0, 0);
                acc[rt][ct] = __builtin_amdgcn_mfma_f32_16x16x32_bf16(a[rt].s8, bh.s8, acc[rt][ct], 0, 0, 0);
            }
        }
    }
#pragma unroll
    for (int rt = 0; rt < 2; ++rt)
#pragma unroll
        for (int reg = 0; reg < 4; ++reg) {
            int row = rowbase + rt * 16 + quad * 4 + reg;
            if (row < M) {
                float di = dinv[row];
#pragma unroll
                for (int ct = 0; ct < 8; ++ct)
                    Hq[((size_t)(ct >> 1) * M + row) * 32 + (ct & 1) * 16 + l15] =
                        rne_bf16(acc[rt][ct][reg] * di);
            }
        }
}

// ============ quarter gather v6: 8 rows in flight + srcs prefetch + (L1) srcd sidecar ======
// 4-lane groups, uint4/lane (full 64B row per group), direct node order (L2-friendly).
// L1: Hq is UNSCALED; per-edge scale comes from srcd[j] (CONTIGUOUS fp32, 2 float4 loads
// per 8 edges) instead of 8 dependent per-lane dinv gathers. Bit-identical math to R3.
// srcs for iteration k+1 prefetched while processing k (breaks srcs->rows serial chain).
template<bool L1>
__global__ __launch_bounds__(256) void quarter_gather(const uint4* __restrict__ H4,
                                                      const float* __restrict__ dinv,
                                                      const int* __restrict__ rstart,
                                                      const int* __restrict__ rend,
                                                      const ushort* __restrict__ srcs,
                                                      const float* __restrict__ srcd,
                                                      const float* __restrict__ bias,
                                                      void* __restrict__ outv, int N) {
    int t = threadIdx.x;
    int bid = blockIdx.x;
    int sub = bid & 7;
    int q = sub >> 1;
    int n = (bid >> 3) * 128 + (sub & 1) * 64 + (t >> 2);   // one dst per 4-lane group
    if (n >= N) return;
    int l = t & 3;                                          // lane's uint4 within 64B row
    const uint4* Hq4 = H4 + (size_t)q * N * 4;              // quarter table, 4 uint4/node

    float4 bb0 = ((const float4*)bias)[q * 8 + l * 2];
    float4 bb1 = ((const float4*)bias)[q * 8 + l * 2 + 1];

    float di = dinv[n];
    uint4 self = Hq4[(size_t)n * 4 + l];                    // self-loop row
    float sc = L1 ? di : 1.0f;                              // L1: Hq unscaled -> self*di
    float a0 = bflo(self.x) * sc, a1 = bfhi(self.x) * sc, a2 = bflo(self.y) * sc, a3 = bfhi(self.y) * sc;
    float a4 = bflo(self.z) * sc, a5 = bfhi(self.z) * sc, a6 = bflo(self.w) * sc, a7 = bfhi(self.w) * sc;

    int j = rstart[n], end = rend[n];
    int nfull = (end - j) >> 3;                             // full 8-edge groups
    uint4 sv;
    if (nfull > 0) sv = *(const uint4*)(srcs + j);
    for (int g = 0; g < nfull; ++g) {
        uint4 svc = sv;
        if (g + 1 < nfull) sv = *(const uint4*)(srcs + j + 8);   // prefetch next group
        int si[8];
        si[0] = svc.x & 0xFFFF; si[1] = svc.x >> 16;
        si[2] = svc.y & 0xFFFF; si[3] = svc.y >> 16;
        si[4] = svc.z & 0xFFFF; si[5] = svc.z >> 16;
        si[6] = svc.w & 0xFFFF; si[7] = svc.w >> 16;
        uint4 v[8];
#pragma unroll
        for (int i = 0; i < 8; ++i) v[i] = Hq4[(size_t)si[i] * 4 + l];
        if constexpr (L1) {
            float4 dd0 = *(const float4*)(srcd + j);        // contiguous, aligned (j%8==0)
            float4 dd1 = *(const float4*)(srcd + j + 4);
            float dd[8] = {dd0.x, dd0.y, dd0.z, dd0.w, dd1.x, dd1.y, dd1.z, dd1.w};
#pragma unroll
            for (int i = 0; i < 8; ++i) {
                a0 = fmaf(bflo(v[i].x), dd[i], a0); a1 = fmaf(bfhi(v[i].x), dd[i], a1);
                a2 = fmaf(bflo(v[i].y), dd[i], a2); a3 = fmaf(bfhi(v[i].y), dd[i], a3);
                a4 = fmaf(bflo(v[i].z), dd[i], a4); a5 = fmaf(bfhi(v[i].z), dd[i], a5);
                a6 = fmaf(bflo(v[i].w), dd[i], a6); a7 = fmaf(bfhi(v[i].w), dd[i], a7);
            }
        } else {
#pragma unroll
            for (int i = 0; i < 8; ++i) {
                a0 += bflo(v[i].x); a1 += bfhi(v[i].x);
                a2 += bflo(v[i].y); a3 += bfhi(v[i].y);
                a4 += bflo(v[i].z); a5 += bfhi(v[i].z);
                a6 += bflo(v[i].w); a7 += bfhi(v[i].w);
            }
        }
        j += 8;
    }
    for (; j < end; ++j) {
        uint4 v = Hq4[(size_t)srcs[j] * 4 + l];
        if constexpr (L1) {
            float d = srcd[j];
            a0 = fmaf(bflo(v.x), d, a0); a1 = fmaf(bfhi(v.x), d, a1);
            a2 = fmaf(bflo(v.y), d, a2); a3 = fmaf(bfhi(v.y), d, a3);
            a4 = fmaf(bflo(v.z), d, a4); a5 = fmaf(bfhi(v.z), d, a5);
            a6 = fmaf(bflo(v.w), d, a6); a7 = fmaf(bfhi(v.w), d, a7);
        } else {
            a0 += bflo(v.x); a1 += bfhi(v.x); a2 += bflo(v.y); a3 += bfhi(v.y);
            a4 += bflo(v.z); a5 += bfhi(v.z); a6 += bflo(v.w); a7 += bfhi(v.w);
        }
    }
    float o0 = fmaf(a0, di, bb0.x), o1 = fmaf(a1, di, bb0.y);
    float o2 = fmaf(a2, di, bb0.z), o3 = fmaf(a3, di, bb0.w);
    float o4 = fmaf(a4, di, bb1.x), o5 = fmaf(a5, di, bb1.y);
    float o6 = fmaf(a6, di, bb1.z), o7 = fmaf(a7, di, bb1.w);
    if (L1) {
        o0 = fmaxf(o0, 0.f); o1 = fmaxf(o1, 0.f); o2 = fmaxf(o2, 0.f); o3 = fmaxf(o3, 0.f);
        o4 = fmaxf(o4, 0.f); o5 = fmaxf(o5, 0.f); o6 = fmaxf(o6, 0.f); o7 = fmaxf(o7, 0.f);
        uint4 pk;
        pk.x = (uint)rne_bf16(o0) | ((uint)rne_bf16(o1) << 16);
        pk.y = (uint)rne_bf16(o2) | ((uint)rne_bf16(o3) << 16);
        pk.z = (uint)rne_bf16(o4) | ((uint)rne_bf16(o5) << 16);
        pk.w = (uint)rne_bf16(o6) | ((uint)rne_bf16(o7) << 16);
        ((uint4*)outv)[((size_t)q * N + n) * 4 + l] = pk;
    } else {
        float4* op = (float4*)((float*)outv + (size_t)n * DF + q * 32 + l * 8);
        op[0] = make_float4(o0, o1, o2, o3);
        op[1] = make_float4(o4, o5, o6, o7);
    }
}

extern "C" void kernel_launch(void* const* d_in, const int* in_sizes, int n_in,
                              void* d_out, int out_size, void* d_ws, size_t ws_size,
                              hipStream_t stream) {
    const float* x  = (const float*)d_in[0];
    const int*   ei = (const int*)d_in[1];
    const float* W1 = (const float*)d_in[2];
    const float* b1 = (const float*)d_in[3];
    const float* W2 = (const float*)d_in[4];
    const float* b2 = (const float*)d_in[5];

    const int N = in_sizes[0] / DF;     // 50000
    const int E = in_sizes[1] / 2;      // 800000
    const int* src = ei;
    const int* dstp = ei + E;
    const int NB = (N + 255) >> 8;      // 196 coarse buckets
    const int SB = (E + SCHUNK - 1) / SCHUNK;   // 391 scatter blocks

    float* out = (float*)d_out;
    char* ws = (char*)d_ws;
    size_t off = 0;
    auto carve = [&](size_t bytes) { void* p = ws + off; off += (bytes + 255) & ~(size_t)255; return p; };
    ushort* Hq     = (ushort*)carve((size_t)N * DF * sizeof(ushort));     // 12.8 MB, quarter-major
    ushort* Z1     = (ushort*)carve((size_t)N * DF * sizeof(ushort));     // 12.8 MB, quarter-major
    float*  dinv   = (float*)carve((size_t)N * sizeof(float));
    int*    rstart = (int*)carve((size_t)N * sizeof(int));
    int*    rend   = (int*)carve((size_t)N * sizeof(int));
    uint*   ebuf   = (uint*)carve((size_t)NB * CAP * sizeof(uint));       // 6.4 MB
    ushort* srcs   = (ushort*)carve((size_t)NB * CAP * sizeof(ushort));   // 3.2 MB
    float*  srcd   = (float*)carve((size_t)NB * CAP * sizeof(float));     // 6.4 MB (dinv[src])
    int*    ccur   = (int*)carve(NBKT_MAX * sizeof(int));
    uint4*  Whi    = (uint4*)carve(2 * 2048 * sizeof(uint4));             // 64 KB
    uint4*  Wlo    = (uint4*)carve(2 * 2048 * sizeof(uint4));             // 64 KB

    const int gemm_b = (N + 127) / 128;         // 391
    const int G1A = (gemm_b + 1) / 2;           // gemm1 blocks in phase A
    const int gath_b = ((N + 127) / 128) * 8;   // (128-dst chunk) x (2 halves x 4 quarters)

    // ---- CSR scatter (scan-free, regs-cached edges) + W split ----
    hipMemsetAsync(ccur, 0, NBKT_MAX * sizeof(int), stream);
    scatter_wprep<<<SB + 16, 256, 0, stream>>>(src, dstp, ccur, ebuf, E, NB, SB, W1, W2, Whi, Wlo);

    // ---- sort phase A (count/scan -> rstart/rend/dinv) || gemm1 first half ----
    sortA_gemm1<<<NB + G1A, 256, 0, stream>>>(ebuf, ccur, rstart, rend, dinv,
                                              x, Whi, Wlo, Hq, NB, N);

    // ---- sort phase B (scatter srcs + srcd=dinv[src]) || gemm1 second half ----
    sortB_gemm1<<<NB + (gemm_b - G1A), 256, 0, stream>>>(ebuf, ccur, rstart, dinv, srcs, srcd,
                                                         x, Whi, Wlo, Hq, NB, N, G1A);

    // ---- layer 1 gather: Z1 = bf16(relu(di*(self*di + sum srcd[j]*Hq[s]) + b1)) ----
    quarter_gather<true><<<gath_b, 256, 0, stream>>>((const uint4*)Hq, dinv, rstart, rend,
                                                     srcs, srcd, b1, Z1, N);

    // ---- layer 2: Hq = bf16((Z1@W2)*dinv); out = gather(Hq)+b2 ----
    gemm_bf16A<<<gemm_b, 256, 0, stream>>>(Z1, Whi + 2048, Wlo + 2048, dinv, Hq, N);
    quarter_gather<false><<<gath_b, 256, 0, stream>>>((const uint4*)Hq, dinv, rstart, rend,
                                                      srcs, srcd, b2, out, N);
}

// Round 5
// 189.528 us; speedup vs baseline: 1.1077x; 1.1077x over previous
//
#include <hip/hip_runtime.h>

#define DF 128
#define NBKT_MAX 256   // coarse buckets = ceil(N/256); N=50000 -> 196
#define CAP 8192       // per-bucket edge capacity incl. 8-align padding (avg 4082+<=1792 pad)
#define SCHUNK 2048    // edges per scatter block (R2: 8192 -> 3.6% occupancy, latency-bound)
// packing assumes src < 2^24 and N < 65535 (srcs stored as ushort; sentinel = N). N=50000.

typedef unsigned int uint;
typedef unsigned short ushort;
typedef __attribute__((ext_vector_type(8))) short short8;   // 8 bf16 (4 VGPR) MFMA A/B frag
typedef __attribute__((ext_vector_type(4))) float f32x4;    // MFMA C/D frag

union frag_u { uint4 u4; short8 s8; };

__device__ __forceinline__ uint f2u(float f) { return __float_as_uint(f); }
__device__ __forceinline__ ushort rne_bf16(float v) {
    uint u = __float_as_uint(v);
    u = u + 0x7FFFu + ((u >> 16) & 1u);
    return (ushort)(u >> 16);
}
__device__ __forceinline__ float bflo(uint u) { return __uint_as_float(u << 16); }
__device__ __forceinline__ float bfhi(uint u) { return __uint_as_float(u & 0xFFFF0000u); }

// ============ scatter + wprep fused (unchanged from R3: 201us best) ============
__global__ __launch_bounds__(256) void scatter_wprep(const int* __restrict__ src,
                                                     const int* __restrict__ dst,
                                                     int* __restrict__ ccur,
                                                     uint* __restrict__ ebuf,
                                                     int E, int NB, int SB,
                                                     const float* __restrict__ W1,
                                                     const float* __restrict__ W2,
                                                     uint4* __restrict__ Whi,
                                                     uint4* __restrict__ Wlo) {
    __shared__ int cnt[NBKT_MAX];
    __shared__ int base[NBKT_MAX];
    int t = threadIdx.x;
    if ((int)blockIdx.x < SB) {
        int e0 = blockIdx.x * SCHUNK;
        int eb0 = e0 + t * 8;                       // this thread's 8 contiguous edges
        int lim = min(E - eb0, 8);                  // <8 only in last block
        int d[8], s[8];
        if (lim == 8) {
            int4 d0 = *(const int4*)(dst + eb0), d1 = *(const int4*)(dst + eb0 + 4);
            int4 s0 = *(const int4*)(src + eb0), s1 = *(const int4*)(src + eb0 + 4);
            d[0] = d0.x; d[1] = d0.y; d[2] = d0.z; d[3] = d0.w;
            d[4] = d1.x; d[5] = d1.y; d[6] = d1.z; d[7] = d1.w;
            s[0] = s0.x; s[1] = s0.y; s[2] = s0.z; s[3] = s0.w;
            s[4] = s1.x; s[5] = s1.y; s[6] = s1.z; s[7] = s1.w;
        } else {
            for (int i = 0; i < 8; ++i) { d[i] = 0; s[i] = 0; }
            for (int i = 0; i < lim; ++i) { d[i] = dst[eb0 + i]; s[i] = src[eb0 + i]; }
        }
        for (int i = t; i < NB; i += 256) cnt[i] = 0;
        __syncthreads();
        for (int i = 0; i < 8; ++i)
            if (i < lim) atomicAdd(&cnt[d[i] >> 8], 1);
        __syncthreads();
        for (int i = t; i < NB; i += 256) base[i] = cnt[i] ? atomicAdd(&ccur[i], cnt[i]) : 0;
        __syncthreads();
        for (int i = 0; i < 8; ++i)
            if (i < lim) {
                int b = d[i] >> 8;
                int pos = atomicAdd(&base[b], 1);
                if (pos < CAP) ebuf[(size_t)b * CAP + pos] = ((uint)(d[i] & 255) << 24) | (uint)s[i];
            }
    } else {
        int tt4 = ((int)blockIdx.x - SB) * 256 + t;   // 0..4095
        int wsel = tt4 >> 11;
        int tt = tt4 & 2047;
        const float* W = wsel ? W2 : W1;
        int lane = tt & 63;
        int n  = ((tt >> 6) & 7) * 16 + (lane & 15);
        int k0 = (tt >> 9) * 32 + (lane >> 4) * 8;
        uint hi[4], lo[4];
#pragma unroll
        for (int p = 0; p < 4; ++p) {
            float f0 = W[(size_t)(k0 + 2 * p) * DF + n];
            float f1 = W[(size_t)(k0 + 2 * p + 1) * DF + n];
            uint u0 = f2u(f0), u1 = f2u(f1);
            hi[p] = (u1 & 0xFFFF0000u) | (u0 >> 16);                 // truncation split
            float l0 = f0 - __uint_as_float(u0 & 0xFFFF0000u);       // exact residual
            float l1 = f1 - __uint_as_float(u1 & 0xFFFF0000u);
            lo[p] = (f2u(l1) & 0xFFFF0000u) | (f2u(l0) >> 16);
        }
        Whi[wsel * 2048 + tt] = make_uint4(hi[0], hi[1], hi[2], hi[3]);
        Wlo[wsel * 2048 + tt] = make_uint4(lo[0], lo[1], lo[2], lo[3]);
    }
}

// ============ fused: bucket sort (sentinel-padded segments) || layer-1 GEMM (UNSCALED) =====
// R4 lesson: splitting sort across two dispatches to build a dinv sidecar cost +8us —
// per-lane dinv loads in gather1 were never the bottleneck (gather1 == gather2 cost in R3).
// NEW: pad slots [v, pad8(v)) of each node's segment get sentinel index N, which points at
// a ZEROED dummy row (quarter tables have stride N+1) with dinv[N]=0 -> gathers run pure
// 8-wide iterations with NO serial tail (was: avg 3.5 edges/group at 1-row-in-flight).
__global__ __launch_bounds__(256) void sort_gemm1(const uint* __restrict__ ebuf,
                                                  const int* __restrict__ ccur,
                                                  int* __restrict__ rstart,
                                                  int* __restrict__ rend,
                                                  float* __restrict__ dinv,
                                                  ushort* __restrict__ srcs,
                                                  const float* __restrict__ A,
                                                  const uint4* __restrict__ Bhi,
                                                  const uint4* __restrict__ Blo,
                                                  ushort* __restrict__ Hq,
                                                  int NB, int N) {
    __shared__ int cnt[256];
    __shared__ int sp[256];
    int t = threadIdx.x;
    if ((int)blockIdx.x < NB) {
        // ---------- bucket sort with 8-aligned, sentinel-padded per-node segments ----------
        int b = blockIdx.x;
        int count = min(ccur[b], CAP);
        const uint* eb = ebuf + (size_t)b * CAP;
        if (b == 0) {                        // one-time: zero dummy rows + dinv sentinel
            if (t < 16) {                    // 4 quarters x 64B dummy row (stride N+1)
                size_t byteoff = ((size_t)(t >> 2) * (N + 1) + N) * 64 + (size_t)(t & 3) * 16;
                *(uint4*)((char*)Hq + byteoff) = make_uint4(0u, 0u, 0u, 0u);
            } else if (t == 16) {
                dinv[N] = 0.0f;              // sentinel scale = 0
            }
        }
        cnt[t] = 0;
        __syncthreads();
        for (int j = t; j < count; j += 256) atomicAdd(&cnt[eb[j] >> 24], 1);
        __syncthreads();
        int v = cnt[t];
        int pv = (v + 7) & ~7;              // padded to multiple of 8
        sp[t] = pv;
        __syncthreads();
        for (int off = 1; off < 256; off <<= 1) {
            int x = (t >= off) ? sp[t - off] : 0;
            __syncthreads();
            sp[t] += x;
            __syncthreads();
        }
        int ex = sp[t] - pv;                // exclusive padded offset (multiple of 8)
        int node = b * 256 + t;
        if (node < N) {
            rstart[node] = b * CAP + ex;
            rend[node]   = b * CAP + ex + v;
            dinv[node] = rsqrtf((float)v + 1.0f);   // +1 = self-loop
        }
        // sentinel-fill this node's pad slots (disjoint from all real scatter targets)
        for (int p = ex + v; p < ex + pv && p < CAP; ++p)
            srcs[(size_t)b * CAP + p] = (ushort)N;
        sp[t] = ex;                          // becomes local cursor
        __syncthreads();
        for (int j = t; j < count; j += 256) {
            uint e = eb[j];
            int pos = atomicAdd(&sp[e >> 24], 1);
            if (pos < CAP) srcs[(size_t)b * CAP + pos] = (ushort)(e & 0xFFFFFFu);
        }
    } else {
        // ---------- layer-1 GEMM, fp32 A, 3-product split, UNSCALED output ----------
        const int lane = t & 63;
        const int w = t >> 6;
        const int l15 = lane & 15, quad = lane >> 4;
        const int rowbase = ((int)blockIdx.x - NB) * 128 + w * 32;
        const int M = N;

        f32x4 acc[2][8];
#pragma unroll
        for (int rt = 0; rt < 2; ++rt)
#pragma unroll
            for (int ct = 0; ct < 8; ++ct) acc[rt][ct] = (f32x4){0.f, 0.f, 0.f, 0.f};

        for (int q = 0; q < 4; ++q) {
            frag_u ah[2], al[2];
#pragma unroll
            for (int rt = 0; rt < 2; ++rt) {
                int m = rowbase + rt * 16 + l15;
                if (m >= M) m = M - 1;                  // clamp; stores guarded below
                const float* ap = A + (size_t)m * DF + q * 32 + quad * 8;
                float4 v0 = *(const float4*)ap;
                float4 v1 = *(const float4*)(ap + 4);
                float f[8] = {v0.x, v0.y, v0.z, v0.w, v1.x, v1.y, v1.z, v1.w};
                uint hi[4], lo[4];
#pragma unroll
                for (int p = 0; p < 4; ++p) {
                    uint u0 = f2u(f[2 * p]), u1 = f2u(f[2 * p + 1]);
                    hi[p] = (u1 & 0xFFFF0000u) | (u0 >> 16);
                    float l0 = f[2 * p]     - __uint_as_float(u0 & 0xFFFF0000u);
                    float l1 = f[2 * p + 1] - __uint_as_float(u1 & 0xFFFF0000u);
                    lo[p] = (f2u(l1) & 0xFFFF0000u) | (f2u(l0) >> 16);
                }
                ah[rt].u4 = make_uint4(hi[0], hi[1], hi[2], hi[3]);
                al[rt].u4 = make_uint4(lo[0], lo[1], lo[2], lo[3]);
            }
#pragma unroll
            for (int ct = 0; ct < 8; ++ct) {
                frag_u bh, bl;
                bh.u4 = Bhi[(q * 8 + ct) * 64 + lane];
                bl.u4 = Blo[(q * 8 + ct) * 64 + lane];
#pragma unroll
                for (int rt = 0; rt < 2; ++rt) {
                    acc[rt][ct] = __builtin_amdgcn_mfma_f32_16x16x32_bf16(al[rt].s8, bh.s8, acc[rt][ct], 0, 0, 0);
                    acc[rt][ct] = __builtin_amdgcn_mfma_f32_16x16x32_bf16(ah[rt].s8, bl.s8, acc[rt][ct], 0, 0, 0);
                    acc[rt][ct] = __builtin_amdgcn_mfma_f32_16x16x32_bf16(ah[rt].s8, bh.s8, acc[rt][ct], 0, 0, 0);
                }
            }
        }
        // epilogue: col = ct*16+l15 -> q = ct>>1, d = (ct&1)*16+l15; row = rt*16+quad*4+reg
        // NOTE: quarter tables have stride M+1 (row M = zeroed sentinel row)
#pragma unroll
        for (int rt = 0; rt < 2; ++rt)
#pragma unroll
            for (int reg = 0; reg < 4; ++reg) {
                int row = rowbase + rt * 16 + quad * 4 + reg;
                if (row < M) {
#pragma unroll
                    for (int ct = 0; ct < 8; ++ct)
                        Hq[((size_t)(ct >> 1) * (M + 1) + row) * 32 + (ct & 1) * 16 + l15] =
                            rne_bf16(acc[rt][ct][reg]);
                }
            }
    }
}

// ============ MFMA GEMM (bf16 A quarter-major): Hq = bf16((A@W)*dinv) ============
// input A (Z1) has stride M; output Hq has stride M+1 (sentinel row stays zero).
__global__ __launch_bounds__(256) void gemm_bf16A(const ushort* __restrict__ A,
                                                  const uint4* __restrict__ Bhi,
                                                  const uint4* __restrict__ Blo,
                                                  const float* __restrict__ dinv,
                                                  ushort* __restrict__ Hq, int M) {
    const int lane = threadIdx.x & 63;
    const int w = threadIdx.x >> 6;
    const int l15 = lane & 15, quad = lane >> 4;
    const int rowbase = blockIdx.x * 128 + w * 32;

    f32x4 acc[2][8];
#pragma unroll
    for (int rt = 0; rt < 2; ++rt)
#pragma unroll
        for (int ct = 0; ct < 8; ++ct) acc[rt][ct] = (f32x4){0.f, 0.f, 0.f, 0.f};

    for (int q = 0; q < 4; ++q) {
        frag_u a[2];
#pragma unroll
        for (int rt = 0; rt < 2; ++rt) {
            int m = rowbase + rt * 16 + l15;
            if (m >= M) m = M - 1;
            const ushort* ap = A + ((size_t)q * M + m) * 32 + quad * 8;
            a[rt].u4 = *(const uint4*)ap;
        }
#pragma unroll
        for (int ct = 0; ct < 8; ++ct) {
            frag_u bh, bl;
            bh.u4 = Bhi[(q * 8 + ct) * 64 + lane];
            bl.u4 = Blo[(q * 8 + ct) * 64 + lane];
#pragma unroll
            for (int rt = 0; rt < 2; ++rt) {
                acc[rt][ct] = __builtin_amdgcn_mfma_f32_16x16x32_bf16(a[rt].s8, bl.s8, acc[rt][ct], 0, 0, 0);
                acc[rt][ct] = __builtin_amdgcn_mfma_f32_16x16x32_bf16(a[rt].s8, bh.s8, acc[rt][ct], 0, 0, 0);
            }
        }
    }
#pragma unroll
    for (int rt = 0; rt < 2; ++rt)
#pragma unroll
        for (int reg = 0; reg < 4; ++reg) {
            int row = rowbase + rt * 16 + quad * 4 + reg;
            if (row < M) {
                float di = dinv[row];
#pragma unroll
                for (int ct = 0; ct < 8; ++ct)
                    Hq[((size_t)(ct >> 1) * (M + 1) + row) * 32 + (ct & 1) * 16 + l15] =
                        rne_bf16(acc[rt][ct][reg] * di);
            }
        }
}

// ============ quarter gather v7: tail-free 8-wide loop (sentinel pads) ============
// 4-lane groups, uint4/lane (full 64B row per group), direct node order (L2-friendly:
// XCD i only streams quarter table (bid&7)>>1 — 3.2MB, L2-resident).
// Segments are sentinel-padded to x8: EVERY iteration is the full 8-rows-in-flight form;
// sentinel rows are a single hot zero line (and dinv[N]=0 for L1), contributing exact 0.
template<bool L1>
__global__ __launch_bounds__(256) void quarter_gather(const uint4* __restrict__ H4,
                                                      const float* __restrict__ dinv,
                                                      const int* __restrict__ rstart,
                                                      const int* __restrict__ rend,
                                                      const ushort* __restrict__ srcs,
                                                      const float* __restrict__ bias,
                                                      void* __restrict__ outv, int N) {
    int t = threadIdx.x;
    int bid = blockIdx.x;
    int sub = bid & 7;
    int q = sub >> 1;
    int n = (bid >> 3) * 128 + (sub & 1) * 64 + (t >> 2);   // one dst per 4-lane group
    if (n >= N) return;
    int l = t & 3;                                          // lane's uint4 within 64B row
    const uint4* Hq4 = H4 + (size_t)q * (N + 1) * 4;        // quarter table, stride N+1

    float4 bb0 = ((const float4*)bias)[q * 8 + l * 2];
    float4 bb1 = ((const float4*)bias)[q * 8 + l * 2 + 1];

    float di = dinv[n];
    uint4 self = Hq4[(size_t)n * 4 + l];                    // self-loop row
    float sc = L1 ? di : 1.0f;                              // L1: Hq unscaled -> self*di
    float a0 = bflo(self.x) * sc, a1 = bfhi(self.x) * sc, a2 = bflo(self.y) * sc, a3 = bfhi(self.y) * sc;
    float a4 = bflo(self.z) * sc, a5 = bfhi(self.z) * sc, a6 = bflo(self.w) * sc, a7 = bfhi(self.w) * sc;

    int j = rstart[n];
    int niter = (rend[n] - j + 7) >> 3;                     // padded trip count (no tail!)
    uint4 sv;
    if (niter > 0) sv = *(const uint4*)(srcs + j);
    for (int g = 0; g < niter; ++g) {
        uint4 svc = sv;
        if (g + 1 < niter) sv = *(const uint4*)(srcs + j + 8);   // prefetch next group
        int si[8];
        si[0] = svc.x & 0xFFFF; si[1] = svc.x >> 16;
        si[2] = svc.y & 0xFFFF; si[3] = svc.y >> 16;
        si[4] = svc.z & 0xFFFF; si[5] = svc.z >> 16;
        si[6] = svc.w & 0xFFFF; si[7] = svc.w >> 16;
        uint4 v[8];
#pragma unroll
        for (int i = 0; i < 8; ++i) v[i] = Hq4[(size_t)si[i] * 4 + l];
        if constexpr (L1) {
            float dd[8];
#pragma unroll
            for (int i = 0; i < 8; ++i) dd[i] = dinv[si[i]];    // sentinel -> 0.0f
#pragma unroll
            for (int i = 0; i < 8; ++i) {
                a0 = fmaf(bflo(v[i].x), dd[i], a0); a1 = fmaf(bfhi(v[i].x), dd[i], a1);
                a2 = fmaf(bflo(v[i].y), dd[i], a2); a3 = fmaf(bfhi(v[i].y), dd[i], a3);
                a4 = fmaf(bflo(v[i].z), dd[i], a4); a5 = fmaf(bfhi(v[i].z), dd[i], a5);
                a6 = fmaf(bflo(v[i].w), dd[i], a6); a7 = fmaf(bfhi(v[i].w), dd[i], a7);
            }
        } else {
#pragma unroll
            for (int i = 0; i < 8; ++i) {                       // sentinel rows are zero
                a0 += bflo(v[i].x); a1 += bfhi(v[i].x);
                a2 += bflo(v[i].y); a3 += bfhi(v[i].y);
                a4 += bflo(v[i].z); a5 += bfhi(v[i].z);
                a6 += bflo(v[i].w); a7 += bfhi(v[i].w);
            }
        }
        j += 8;
    }
    float o0 = fmaf(a0, di, bb0.x), o1 = fmaf(a1, di, bb0.y);
    float o2 = fmaf(a2, di, bb0.z), o3 = fmaf(a3, di, bb0.w);
    float o4 = fmaf(a4, di, bb1.x), o5 = fmaf(a5, di, bb1.y);
    float o6 = fmaf(a6, di, bb1.z), o7 = fmaf(a7, di, bb1.w);
    if (L1) {
        o0 = fmaxf(o0, 0.f); o1 = fmaxf(o1, 0.f); o2 = fmaxf(o2, 0.f); o3 = fmaxf(o3, 0.f);
        o4 = fmaxf(o4, 0.f); o5 = fmaxf(o5, 0.f); o6 = fmaxf(o6, 0.f); o7 = fmaxf(o7, 0.f);
        uint4 pk;
        pk.x = (uint)rne_bf16(o0) | ((uint)rne_bf16(o1) << 16);
        pk.y = (uint)rne_bf16(o2) | ((uint)rne_bf16(o3) << 16);
        pk.z = (uint)rne_bf16(o4) | ((uint)rne_bf16(o5) << 16);
        pk.w = (uint)rne_bf16(o6) | ((uint)rne_bf16(o7) << 16);
        ((uint4*)outv)[((size_t)q * N + n) * 4 + l] = pk;      // Z1 keeps stride N
    } else {
        float4* op = (float4*)((float*)outv + (size_t)n * DF + q * 32 + l * 8);
        op[0] = make_float4(o0, o1, o2, o3);
        op[1] = make_float4(o4, o5, o6, o7);
    }
}

extern "C" void kernel_launch(void* const* d_in, const int* in_sizes, int n_in,
                              void* d_out, int out_size, void* d_ws, size_t ws_size,
                              hipStream_t stream) {
    const float* x  = (const float*)d_in[0];
    const int*   ei = (const int*)d_in[1];
    const float* W1 = (const float*)d_in[2];
    const float* b1 = (const float*)d_in[3];
    const float* W2 = (const float*)d_in[4];
    const float* b2 = (const float*)d_in[5];

    const int N = in_sizes[0] / DF;     // 50000
    const int E = in_sizes[1] / 2;      // 800000
    const int* src = ei;
    const int* dstp = ei + E;
    const int NB = (N + 255) >> 8;      // 196 coarse buckets
    const int SB = (E + SCHUNK - 1) / SCHUNK;   // 391 scatter blocks

    float* out = (float*)d_out;
    char* ws = (char*)d_ws;
    size_t off = 0;
    auto carve = [&](size_t bytes) { void* p = ws + off; off += (bytes + 255) & ~(size_t)255; return p; };
    ushort* Hq     = (ushort*)carve((size_t)4 * (N + 1) * 32 * sizeof(ushort) * 2); // 12.8MB+256B, stride N+1
    ushort* Z1     = (ushort*)carve((size_t)N * DF * sizeof(ushort));     // 12.8 MB, stride N
    float*  dinv   = (float*)carve((size_t)(N + 1) * sizeof(float));      // + sentinel slot
    int*    rstart = (int*)carve((size_t)N * sizeof(int));
    int*    rend   = (int*)carve((size_t)N * sizeof(int));
    uint*   ebuf   = (uint*)carve((size_t)NB * CAP * sizeof(uint));       // 6.4 MB
    ushort* srcs   = (ushort*)carve((size_t)NB * CAP * sizeof(ushort));   // 3.2 MB
    int*    ccur   = (int*)carve(NBKT_MAX * sizeof(int));
    uint4*  Whi    = (uint4*)carve(2 * 2048 * sizeof(uint4));             // 64 KB
    uint4*  Wlo    = (uint4*)carve(2 * 2048 * sizeof(uint4));             // 64 KB

    const int gemm_b = (N + 127) / 128;         // 391
    const int gath_b = ((N + 127) / 128) * 8;   // (128-dst chunk) x (2 halves x 4 quarters)

    // ---- CSR scatter (scan-free, regs-cached edges) + W split ----
    hipMemsetAsync(ccur, 0, NBKT_MAX * sizeof(int), stream);
    scatter_wprep<<<SB + 16, 256, 0, stream>>>(src, dstp, ccur, ebuf, E, NB, SB, W1, W2, Whi, Wlo);

    // ---- bucket sort (sentinel-padded segments) OVERLAPPED with layer-1 GEMM (unscaled) ----
    sort_gemm1<<<NB + gemm_b, 256, 0, stream>>>(ebuf, ccur, rstart, rend, dinv, srcs,
                                                x, Whi, Wlo, Hq, NB, N);

    // ---- layer 1 gather: Z1 = bf16(relu(di*(self*di + sum dinv[s]*Hq[s]) + b1)) ----
    quarter_gather<true><<<gath_b, 256, 0, stream>>>((const uint4*)Hq, dinv, rstart, rend,
                                                     srcs, b1, Z1, N);

    // ---- layer 2: Hq = bf16((Z1@W2)*dinv); out = gather(Hq)+b2 ----
    gemm_bf16A<<<gemm_b, 256, 0, stream>>>(Z1, Whi + 2048, Wlo + 2048, dinv, Hq, N);
    quarter_gather<false><<<gath_b, 256, 0, stream>>>((const uint4*)Hq, dinv, rstart, rend,
                                                      srcs, b2, out, N);
}